// Round 1
// baseline (170.391 us; speedup 1.0000x reference)
//
#include <hip/hip_runtime.h>
#include <math.h>

#define BLOCK 256

// Kernel A: partial risk-set sums.
// grid: (n/BLOCK, nbj). partial[bj*n + i] = sum_{j in slice bj} exp(theta_j) * (T[j] >= T[i])
__global__ void surv_partial(const float* __restrict__ theta,
                             const float* __restrict__ T,
                             float* __restrict__ partial,
                             int n, int slice) {
    __shared__ float sT[BLOCK];
    __shared__ float sE[BLOCK];
    const int tid = threadIdx.x;
    const int i = blockIdx.x * BLOCK + tid;
    const int j0 = blockIdx.y * slice;
    const int j1 = j0 + slice;
    const float Ti = T[i];
    float acc = 0.0f;
    for (int jt = j0; jt < j1; jt += BLOCK) {
        __syncthreads();
        sT[tid] = T[jt + tid];
        sE[tid] = expf(theta[jt + tid]);
        __syncthreads();
#pragma unroll 8
        for (int k = 0; k < BLOCK; ++k) {
            acc += (sT[k] >= Ti) ? sE[k] : 0.0f;
        }
    }
    partial[(size_t)blockIdx.y * n + i] = acc;
}

// Kernel B: per-i term + block reduction -> one partial sum per block.
__global__ void surv_terms(const float* __restrict__ theta,
                           const float* __restrict__ events,
                           const float* __restrict__ partial,
                           float* __restrict__ bsum,
                           int n, int nbj) {
    __shared__ float red[BLOCK];
    const int tid = threadIdx.x;
    const int i = blockIdx.x * BLOCK + tid;
    float risk = 0.0f;
    for (int b = 0; b < nbj; ++b) risk += partial[(size_t)b * n + i];
    float term = (theta[i] - logf(risk)) * events[i];
    red[tid] = term;
    __syncthreads();
    for (int s = BLOCK / 2; s > 0; s >>= 1) {
        if (tid < s) red[tid] += red[tid + s];
        __syncthreads();
    }
    if (tid == 0) bsum[blockIdx.x] = red[0];
}

// Kernel C: one wave reduces the per-block sums, writes -mean.
__global__ void surv_final(const float* __restrict__ bsum,
                           float* __restrict__ out,
                           int nblocks, int n) {
    const int tid = threadIdx.x;
    float v = (tid < nblocks) ? bsum[tid] : 0.0f;
    for (int off = 32; off > 0; off >>= 1) v += __shfl_down(v, off, 64);
    if (tid == 0) out[0] = -v / (float)n;
}

extern "C" void kernel_launch(void* const* d_in, const int* in_sizes, int n_in,
                              void* d_out, int out_size, void* d_ws, size_t ws_size,
                              hipStream_t stream) {
    const float* theta  = (const float*)d_in[0];
    const float* T      = (const float*)d_in[1];
    const float* events = (const float*)d_in[2];
    float* out = (float*)d_out;

    const int n = in_sizes[0];          // 16384
    const int nbi = n / BLOCK;          // 64

    int nbj = 8;                        // j-dimension split for occupancy
    size_t need = (size_t)nbj * n * sizeof(float) + (size_t)nbi * sizeof(float);
    if (ws_size < need) nbj = 1;        // fallback: 64KB + 256B
    const int slice = n / nbj;

    float* partial = (float*)d_ws;
    float* bsum    = partial + (size_t)nbj * n;

    surv_partial<<<dim3(nbi, nbj), BLOCK, 0, stream>>>(theta, T, partial, n, slice);
    surv_terms<<<nbi, BLOCK, 0, stream>>>(theta, events, partial, bsum, n, nbj);
    surv_final<<<1, 64, 0, stream>>>(bsum, out, nbi, n);
}

// Round 2
// 102.400 us; speedup vs baseline: 1.6640x; 1.6640x over previous
//
#include <hip/hip_runtime.h>
#include <math.h>

#define BLOCK 256

// Kernel 0: E[j] = exp(theta[j])
__global__ void surv_exp(const float* __restrict__ theta,
                         float* __restrict__ E, int n) {
    int i = blockIdx.x * BLOCK + threadIdx.x;
    if (i < n) E[i] = expf(theta[i]);
}

// Kernel A: partial risk-set sums, 4 i's per thread, scalar-load j-stream.
// grid: (n/(4*BLOCK), nbj). partial[bj*n + i] = sum_{j in slice} E[j]*(T[j]>=T[i])
__global__ void surv_partial(const float* __restrict__ T,
                             const float* __restrict__ E,
                             float* __restrict__ partial,
                             int n, int slice) {
    const int tid = threadIdx.x;
    const int q = n >> 2;                        // 4096
    const int i0 = blockIdx.x * BLOCK + tid;     // thread's 4 i's: i0 + k*q
    const int j0 = blockIdx.y * slice;
    const int j1 = j0 + slice;

    const float T0 = T[i0];
    const float T1 = T[i0 + q];
    const float T2 = T[i0 + 2 * q];
    const float T3 = T[i0 + 3 * q];
    float a0 = 0.f, a1 = 0.f, a2 = 0.f, a3 = 0.f;

#pragma unroll 8
    for (int j = j0; j < j1; ++j) {
        const float Tj = T[j];   // wave-uniform -> scalar load
        const float Ej = E[j];   // wave-uniform -> scalar load
        a0 += (Tj >= T0) ? Ej : 0.f;
        a1 += (Tj >= T1) ? Ej : 0.f;
        a2 += (Tj >= T2) ? Ej : 0.f;
        a3 += (Tj >= T3) ? Ej : 0.f;
    }

    float* p = partial + (size_t)blockIdx.y * n;
    p[i0]         = a0;
    p[i0 + q]     = a1;
    p[i0 + 2 * q] = a2;
    p[i0 + 3 * q] = a3;
}

// Kernel B: per-i term + block reduction -> one partial sum per block.
__global__ void surv_terms(const float* __restrict__ theta,
                           const float* __restrict__ events,
                           const float* __restrict__ partial,
                           float* __restrict__ bsum,
                           int n, int nbj) {
    __shared__ float red[BLOCK];
    const int tid = threadIdx.x;
    const int i = blockIdx.x * BLOCK + tid;
    float risk = 0.0f;
    for (int b = 0; b < nbj; ++b) risk += partial[(size_t)b * n + i];
    float term = (theta[i] - logf(risk)) * events[i];
    red[tid] = term;
    __syncthreads();
    for (int s = BLOCK / 2; s > 0; s >>= 1) {
        if (tid < s) red[tid] += red[tid + s];
        __syncthreads();
    }
    if (tid == 0) bsum[blockIdx.x] = red[0];
}

// Kernel C: one wave reduces the per-block sums, writes -mean.
__global__ void surv_final(const float* __restrict__ bsum,
                           float* __restrict__ out,
                           int nblocks, int n) {
    const int tid = threadIdx.x;
    float v = (tid < nblocks) ? bsum[tid] : 0.0f;
    for (int off = 32; off > 0; off >>= 1) v += __shfl_down(v, off, 64);
    if (tid == 0) out[0] = -v / (float)n;
}

extern "C" void kernel_launch(void* const* d_in, const int* in_sizes, int n_in,
                              void* d_out, int out_size, void* d_ws, size_t ws_size,
                              hipStream_t stream) {
    const float* theta  = (const float*)d_in[0];
    const float* T      = (const float*)d_in[1];
    const float* events = (const float*)d_in[2];
    float* out = (float*)d_out;

    const int n = in_sizes[0];          // 16384
    const int nbi = n / BLOCK;          // 64 (for terms kernel)
    const int nbiA = n / (4 * BLOCK);   // 16 (i-blocks for partial kernel)

    // choose j-split by available workspace: partial (nbj*n) + E (n) + bsum (nbi)
    int nbj = 64;
    while (nbj > 1) {
        size_t need = ((size_t)nbj * n + n + nbi) * sizeof(float);
        if (need <= ws_size) break;
        nbj >>= 1;
    }
    const int slice = n / nbj;

    float* partial = (float*)d_ws;
    float* E       = partial + (size_t)nbj * n;
    float* bsum    = E + n;

    surv_exp<<<(n + BLOCK - 1) / BLOCK, BLOCK, 0, stream>>>(theta, E, n);
    surv_partial<<<dim3(nbiA, nbj), BLOCK, 0, stream>>>(T, E, partial, n, slice);
    surv_terms<<<nbi, BLOCK, 0, stream>>>(theta, events, partial, bsum, n, nbj);
    surv_final<<<1, 64, 0, stream>>>(bsum, out, nbi, n);
}